// Round 1
// baseline (1905.210 us; speedup 1.0000x reference)
//
#include <hip/hip_runtime.h>
#include <cstdint>
#include <cstddef>

#define B_ 4
#define N_ 8192
#define C_ 128
#define CZ_ 16
#define H_ 4
#define CH_ 32
#define NQ_ 32
#define NK_ 128
#define NB_ 256
#define EPS_ 1e-5f
#define INF_ 1000000000.0f

typedef unsigned int u32;
typedef unsigned short u16;

__device__ __forceinline__ float bflo(u32 p){ union{u32 i; float f;} x; x.i = p<<16; return x.f; }
__device__ __forceinline__ float bfhi(u32 p){ union{u32 i; float f;} x; x.i = p & 0xffff0000u; return x.f; }
__device__ __forceinline__ void up8(uint4 p, float* o){
  o[0]=bflo(p.x); o[1]=bfhi(p.x); o[2]=bflo(p.y); o[3]=bfhi(p.y);
  o[4]=bflo(p.z); o[5]=bfhi(p.z); o[6]=bflo(p.w); o[7]=bfhi(p.w);
}
__device__ __forceinline__ u16 f2bf(float f){ union{float f; u32 i;} x; x.f=f; u32 r = x.i + 0x7fffu + ((x.i>>16)&1u); return (u16)(r>>16); }
__device__ __forceinline__ u32 pk2(float a, float b){ return (u32)f2bf(a) | ((u32)f2bf(b)<<16); }
__device__ __forceinline__ float sigm(float x){ return 1.f/(1.f+__expf(-x)); }

#define FMA16(ACC, WPTR, S) do { \
  const float4* _wr = (const float4*)(WPTR); \
  float4 _w0=_wr[0], _w1=_wr[1], _w2=_wr[2], _w3=_wr[3]; \
  ACC[0]+=(S)*_w0.x; ACC[1]+=(S)*_w0.y; ACC[2]+=(S)*_w0.z; ACC[3]+=(S)*_w0.w; \
  ACC[4]+=(S)*_w1.x; ACC[5]+=(S)*_w1.y; ACC[6]+=(S)*_w1.z; ACC[7]+=(S)*_w1.w; \
  ACC[8]+=(S)*_w2.x; ACC[9]+=(S)*_w2.y; ACC[10]+=(S)*_w2.z; ACC[11]+=(S)*_w2.w; \
  ACC[12]+=(S)*_w3.x; ACC[13]+=(S)*_w3.y; ACC[14]+=(S)*_w3.z; ACC[15]+=(S)*_w3.w; } while(0)

#define FMA8x2(A0, A1, WPTR, S0, S1) do { \
  const float4* _wr = (const float4*)(WPTR); \
  float4 _w0=_wr[0], _w1=_wr[1]; \
  A0[0]+=(S0)*_w0.x; A0[1]+=(S0)*_w0.y; A0[2]+=(S0)*_w0.z; A0[3]+=(S0)*_w0.w; \
  A0[4]+=(S0)*_w1.x; A0[5]+=(S0)*_w1.y; A0[6]+=(S0)*_w1.z; A0[7]+=(S0)*_w1.w; \
  A1[0]+=(S1)*_w0.x; A1[1]+=(S1)*_w0.y; A1[2]+=(S1)*_w0.z; A1[3]+=(S1)*_w0.w; \
  A1[4]+=(S1)*_w1.x; A1[5]+=(S1)*_w1.y; A1[6]+=(S1)*_w1.z; A1[7]+=(S1)*_w1.w; } while(0)

// LDS arena (63,008 B):
//   A_BF  [128][136] bf16 : skn -> ak                      @ 0      (34816 B)
//   BQ_BF [ 32][136] bf16 : sqn -> aq -> q_all -> g*o      @ 34816  (8704 B)
//   H1_BF [ 32][136] bf16 : kT_h -> attn_h                 @ 43520  (8704 B)
//   H2_BF [ 32][136] bf16 : vT_h                           @ 52224  (8704 B)
//   SQF   [ 32][136] f32  : raw s_q (overlays H1+H2)       @ 43520  (17408 B)
//   ASTAT [160][2]   f32  : a-row (mean, rstd)             @ 60928  (1280 B)
//   KMV   [128]      f32  : key mask*valid                 @ 62208  (512 B)
//   WZE   [16][4]    f32  : ln_z_w * W_z                   @ 62720  (256 B)
//   WZT   [4], WZC [4] f32                                 @ 62976 / 62992

__global__ __launch_bounds__(256, 2)
void capb_kernel(const float* __restrict__ ga, const float* __restrict__ gz, const float* __restrict__ gs,
    const float* __restrict__ gmask, const float* __restrict__ lnsqw, const float* __restrict__ Wgq,
    const float* __restrict__ bgq, const float* __restrict__ Wbq, const float* __restrict__ lnskw,
    const float* __restrict__ Wgk, const float* __restrict__ bgk, const float* __restrict__ Wbk,
    const float* __restrict__ lnzw, const float* __restrict__ lnzb, const float* __restrict__ Wz,
    const float* __restrict__ Wq, const float* __restrict__ Wk, const float* __restrict__ Wv,
    const float* __restrict__ Wg, const float* __restrict__ bgv, const float* __restrict__ Wo,
    const float* __restrict__ bo, const float* __restrict__ Wado, const float* __restrict__ bado,
    float* __restrict__ gout)
{
  __shared__ alignas(16) char arena[63008];
  u16* const A_BF  = (u16*)(arena);
  u16* const BQ_BF = (u16*)(arena + 34816);
  u16* const H1_BF = (u16*)(arena + 43520);
  u16* const H2_BF = (u16*)(arena + 52224);
  float* const SQF   = (float*)(arena + 43520);
  float* const ASTAT = (float*)(arena + 60928);
  float* const KMV   = (float*)(arena + 62208);
  float* const WZE   = (float*)(arena + 62720);
  float* const WZT   = (float*)(arena + 62976);
  float* const WZC   = (float*)(arena + 62992);

  const int i = blockIdx.x;     // window block index (nb)
  const int b = blockIdx.y;
  const int tid = (int)threadIdx.x;
  const int start = i*NQ_ - (NK_-NQ_)/2;

  // ---------------- Phase 0: LN rows, a-row stats, key mask, z constants ----------------
  {
    const int slot = tid >> 5, l32 = tid & 31;
    #pragma unroll 1
    for (int task = slot; task < 320; task += 8) {
      const float* src = ga; const float* wv = lnsqw; u16* dst = BQ_BF;
      int statrow = 0; int grow = 0; bool isS = false;
      if (task < 32) {
        int r = task; grow = i*NQ_ + r; src = gs; wv = lnsqw; dst = BQ_BF + r*136; isS = true;
      } else if (task < 160) {
        int r = task-32; int raw = start + r; int g = min(max(raw,0), N_-1);
        grow = g; src = gs; wv = lnskw; dst = A_BF + r*136; isS = true;
        if (l32 == 0) KMV[r] = ((raw >= 0 && raw < N_) ? 1.f : 0.f) * gmask[(size_t)b*N_ + g];
      } else if (task < 192) {
        int r = task-160; grow = i*NQ_ + r; src = ga; isS = false; statrow = r;
      } else {
        int r = task-192; int raw = start + r; int g = min(max(raw,0), N_-1);
        grow = g; src = ga; isS = false; statrow = 32 + r;
      }
      float4 v4 = *(const float4*)(src + ((size_t)b*N_ + grow)*C_ + l32*4);
      float sm = v4.x+v4.y+v4.z+v4.w;
      float sq = v4.x*v4.x+v4.y*v4.y+v4.z*v4.z+v4.w*v4.w;
      #pragma unroll
      for (int m=1; m<32; m<<=1){ sm += __shfl_xor(sm,m); sq += __shfl_xor(sq,m); }
      float mean = sm*(1.f/128.f);
      float var  = sq*(1.f/128.f) - mean*mean;
      float rstd = rsqrtf(var + EPS_);
      if (isS) {
        float4 w4 = *(const float4*)(wv + l32*4);
        u32 lo = pk2((v4.x-mean)*rstd*w4.x, (v4.y-mean)*rstd*w4.y);
        u32 hi = pk2((v4.z-mean)*rstd*w4.z, (v4.w-mean)*rstd*w4.w);
        *((uint2*)(dst + l32*4)) = make_uint2(lo, hi);
      } else if (l32 == 0) {
        ASTAT[statrow*2] = mean; ASTAT[statrow*2+1] = rstd;
      }
    }
    if (tid < 64) WZE[tid] = lnzw[tid>>2] * Wz[tid];
    else if (tid < 68) { int h = tid-64; float t=0; for (int c=0;c<16;c++) t += lnzw[c]*Wz[c*4+h]; WZT[h]=t; }
    else if (tid < 72) { int h = tid-68; float t=0; for (int c=0;c<16;c++) t += lnzb[c]*Wz[c*4+h]; WZC[h]=t; }
  }
  __syncthreads();

  const int qi  = tid >> 3;       // 0..31
  const int cg  = tid & 7;        // 0..7
  const int c16 = cg*16;
  const int r0  = (tid>>5)*16;    // ak tile: 16 rows
  const int c4  = (tid&31)*4;     // ak tile: 4 cols
  const int r2  = (tid>>2)*2;     // k/v staging: 2 rows
  const int cq8 = (tid&3)*8;      // k/v staging: 8 cols in head

  // ---------------- Phase 1: aq (32x128) and ak (128x128) ----------------
  float aqv[16];
  {
    float acc[16];
    #pragma unroll
    for (int c=0;c<16;c++) acc[c]=0.f;
    const u16* srow = BQ_BF + qi*136;
    #pragma unroll 1
    for (int j0=0;j0<128;j0+=8){
      uint4 p = *(const uint4*)(srow + j0);
      float av[8]; up8(p, av);
      #pragma unroll
      for (int jj=0;jj<8;jj++) FMA16(acc, Wgq + (size_t)(j0+jj)*C_ + c16, av[jj]);
    }
    const float am = ASTAT[qi*2], ar = ASTAT[qi*2+1];
    const float* arow = ga + ((size_t)b*N_ + (size_t)i*NQ_ + qi)*C_ + c16;
    #pragma unroll
    for (int t4=0;t4<4;t4++){
      float4 a4 = *(const float4*)(arow + t4*4);
      float4 b4 = *(const float4*)(bgq + c16 + t4*4);
      aqv[t4*4+0] = sigm(acc[t4*4+0]+b4.x)*((a4.x-am)*ar);
      aqv[t4*4+1] = sigm(acc[t4*4+1]+b4.y)*((a4.y-am)*ar);
      aqv[t4*4+2] = sigm(acc[t4*4+2]+b4.z)*((a4.z-am)*ar);
      aqv[t4*4+3] = sigm(acc[t4*4+3]+b4.w)*((a4.w-am)*ar);
    }
    #pragma unroll 1
    for (int j0=0;j0<128;j0+=8){
      uint4 p = *(const uint4*)(srow + j0);
      float av[8]; up8(p, av);
      #pragma unroll
      for (int jj=0;jj<8;jj++) FMA16(aqv, Wbq + (size_t)(j0+jj)*C_ + c16, av[jj]);
    }
  }
  float akv[64];
  {
    float acc[64];
    #pragma unroll
    for (int x=0;x<64;x++) acc[x]=0.f;
    #pragma unroll 1
    for (int j0=0;j0<128;j0+=8){
      float wv[8][4];
      #pragma unroll
      for (int jj=0;jj<8;jj++){
        float4 w = *(const float4*)(Wgk + (size_t)(j0+jj)*C_ + c4);
        wv[jj][0]=w.x; wv[jj][1]=w.y; wv[jj][2]=w.z; wv[jj][3]=w.w;
      }
      #pragma unroll
      for (int r=0;r<16;r++){
        uint4 p = *(const uint4*)(A_BF + (r0+r)*136 + j0);
        float av[8]; up8(p,av);
        #pragma unroll
        for (int jj=0;jj<8;jj++){
          acc[r*4+0]+=av[jj]*wv[jj][0]; acc[r*4+1]+=av[jj]*wv[jj][1];
          acc[r*4+2]+=av[jj]*wv[jj][2]; acc[r*4+3]+=av[jj]*wv[jj][3];
        }
      }
    }
    float4 bk4 = *(const float4*)(bgk + c4);
    #pragma unroll
    for (int r=0;r<16;r++){
      int raw = start + r0 + r; int g = min(max(raw,0), N_-1);
      float4 a4 = *(const float4*)(ga + ((size_t)b*N_ + g)*C_ + c4);
      float am = ASTAT[(32+r0+r)*2], ar2 = ASTAT[(32+r0+r)*2+1];
      akv[r*4+0] = sigm(acc[r*4+0]+bk4.x)*((a4.x-am)*ar2);
      akv[r*4+1] = sigm(acc[r*4+1]+bk4.y)*((a4.y-am)*ar2);
      akv[r*4+2] = sigm(acc[r*4+2]+bk4.z)*((a4.z-am)*ar2);
      akv[r*4+3] = sigm(acc[r*4+3]+bk4.w)*((a4.w-am)*ar2);
    }
    #pragma unroll 1
    for (int j0=0;j0<128;j0+=8){
      float wv[8][4];
      #pragma unroll
      for (int jj=0;jj<8;jj++){
        float4 w = *(const float4*)(Wbk + (size_t)(j0+jj)*C_ + c4);
        wv[jj][0]=w.x; wv[jj][1]=w.y; wv[jj][2]=w.z; wv[jj][3]=w.w;
      }
      #pragma unroll
      for (int r=0;r<16;r++){
        uint4 p = *(const uint4*)(A_BF + (r0+r)*136 + j0);
        float av[8]; up8(p,av);
        #pragma unroll
        for (int jj=0;jj<8;jj++){
          akv[r*4+0]+=av[jj]*wv[jj][0]; akv[r*4+1]+=av[jj]*wv[jj][1];
          akv[r*4+2]+=av[jj]*wv[jj][2]; akv[r*4+3]+=av[jj]*wv[jj][3];
        }
      }
    }
  }
  __syncthreads();
  {
    u16* d = BQ_BF + qi*136 + c16;
    ((uint2*)d)[0] = make_uint2(pk2(aqv[0],aqv[1]),  pk2(aqv[2],aqv[3]));
    ((uint2*)d)[1] = make_uint2(pk2(aqv[4],aqv[5]),  pk2(aqv[6],aqv[7]));
    ((uint2*)d)[2] = make_uint2(pk2(aqv[8],aqv[9]),  pk2(aqv[10],aqv[11]));
    ((uint2*)d)[3] = make_uint2(pk2(aqv[12],aqv[13]),pk2(aqv[14],aqv[15]));
    #pragma unroll
    for (int r=0;r<16;r++){
      *((uint2*)(A_BF + (r0+r)*136 + c4)) =
        make_uint2(pk2(akv[r*4],akv[r*4+1]), pk2(akv[r*4+2],akv[r*4+3]));
    }
  }
  __syncthreads();

  // ---------------- Phase 2: q_all (scaled, bf16 over BQ) and gate g (regs) ----------------
  float gv[16];
  {
    float qacc[16], gacc[16];
    #pragma unroll
    for (int x=0;x<16;x++){ qacc[x]=0.f; gacc[x]=0.f; }
    const u16* arow = BQ_BF + qi*136;
    #pragma unroll 1
    for (int j0=0;j0<128;j0+=8){
      uint4 p = *(const uint4*)(arow + j0);
      float av[8]; up8(p,av);
      #pragma unroll
      for (int jj=0;jj<8;jj++){
        FMA16(qacc, Wq + (size_t)(j0+jj)*C_ + c16, av[jj]);
        #pragma unroll
        for (int h=0;h<4;h++){
          float4 w = *(const float4*)(Wg + (size_t)(j0+jj)*C_ + h*32 + cg*4);
          gacc[h*4+0]+=av[jj]*w.x; gacc[h*4+1]+=av[jj]*w.y;
          gacc[h*4+2]+=av[jj]*w.z; gacc[h*4+3]+=av[jj]*w.w;
        }
      }
    }
    #pragma unroll
    for (int h=0;h<4;h++){
      float4 b4 = *(const float4*)(bgv + h*32 + cg*4);
      gv[h*4+0]=sigm(gacc[h*4+0]+b4.x); gv[h*4+1]=sigm(gacc[h*4+1]+b4.y);
      gv[h*4+2]=sigm(gacc[h*4+2]+b4.z); gv[h*4+3]=sigm(gacc[h*4+3]+b4.w);
    }
    __syncthreads();
    const float scale = 0.17677669529663687f; // 1/sqrt(32)
    u16* d = BQ_BF + qi*136 + c16;
    ((uint2*)d)[0] = make_uint2(pk2(qacc[0]*scale,qacc[1]*scale),  pk2(qacc[2]*scale,qacc[3]*scale));
    ((uint2*)d)[1] = make_uint2(pk2(qacc[4]*scale,qacc[5]*scale),  pk2(qacc[6]*scale,qacc[7]*scale));
    ((uint2*)d)[2] = make_uint2(pk2(qacc[8]*scale,qacc[9]*scale),  pk2(qacc[10]*scale,qacc[11]*scale));
    ((uint2*)d)[3] = make_uint2(pk2(qacc[12]*scale,qacc[13]*scale),pk2(qacc[14]*scale,qacc[15]*scale));
    __syncthreads();
  }

  // ---------------- Phase 3: logits for all 4 heads (registers) ----------------
  float lreg[64];
  #pragma unroll
  for (int x=0;x<64;x++) lreg[x]=0.f;

  #pragma unroll
  for (int h=0;h<4;h++){
    { // stage kT_h into H1: thread computes k[r2..r2+1][cq8..cq8+7] and writes transposed
      float ka0[8], ka1[8];
      #pragma unroll
      for (int x=0;x<8;x++){ ka0[x]=0.f; ka1[x]=0.f; }
      const u16* ar0 = A_BF + r2*136;
      const u16* ar1 = A_BF + (r2+1)*136;
      #pragma unroll 1
      for (int j0=0;j0<128;j0+=8){
        uint4 p0=*(const uint4*)(ar0+j0), p1=*(const uint4*)(ar1+j0);
        float a0[8],a1[8]; up8(p0,a0); up8(p1,a1);
        #pragma unroll
        for (int jj=0;jj<8;jj++)
          FMA8x2(ka0, ka1, Wk + (size_t)(j0+jj)*C_ + h*32 + cq8, a0[jj], a1[jj]);
      }
      #pragma unroll
      for (int c=0;c<8;c++){
        H1_BF[(cq8+c)*136 + r2]   = f2bf(ka0[c]);
        H1_BF[(cq8+c)*136 + r2+1] = f2bf(ka1[c]);
      }
    }
    __syncthreads();
    { // logits: lreg[h*16+kk] += q[qi][h,:] . k[c16+kk][h,:]
      const u16* qp = BQ_BF + qi*136 + h*32;
      const u16* kb = H1_BF + c16;
      #pragma unroll 1
      for (int c0=0;c0<32;c0+=8){
        uint4 qq = *(const uint4*)(qp + c0);
        float qv[8]; up8(qq,qv);
        #pragma unroll
        for (int cc=0;cc<8;cc++){
          const u16* kr = kb + (c0+cc)*136;
          uint4 k0=*(const uint4*)(kr), k1=*(const uint4*)(kr + 8);
          float kv[16]; up8(k0,kv); up8(k1,kv+8);
          #pragma unroll
          for (int kk=0;kk<16;kk++) lreg[h*16+kk] += qv[cc]*kv[kk];
        }
      }
    }
    __syncthreads();
  }

  // ---------------- Phase 4: stream z once; add pair bias + mask bias ----------------
  {
    const float qm = gmask[(size_t)b*N_ + (size_t)i*NQ_ + qi];
    const float* zbase = gz + ((((size_t)b*NB_ + i)*NQ_ + qi)*NK_ + c16)*CZ_;
    #pragma unroll
    for (int kk=0;kk<16;kk++){
      const float* zp = zbase + kk*CZ_;
      float4 z0=*(const float4*)(zp), z1=*(const float4*)(zp+4), z2=*(const float4*)(zp+8), z3=*(const float4*)(zp+12);
      float zv[16] = {z0.x,z0.y,z0.z,z0.w, z1.x,z1.y,z1.z,z1.w, z2.x,z2.y,z2.z,z2.w, z3.x,z3.y,z3.z,z3.w};
      float smz=0.f, sqz=0.f;
      #pragma unroll
      for (int c=0;c<16;c++){ smz+=zv[c]; sqz+=zv[c]*zv[c]; }
      float mz = smz*(1.f/16.f);
      float vz = sqz*(1.f/16.f) - mz*mz;
      float rz = rsqrtf(vz + EPS_);
      float S0=0.f,S1=0.f,S2=0.f,S3=0.f;
      #pragma unroll
      for (int c=0;c<16;c++){
        float4 we = *(const float4*)(WZE + c*4);
        S0+=zv[c]*we.x; S1+=zv[c]*we.y; S2+=zv[c]*we.z; S3+=zv[c]*we.w;
      }
      float bias = INF_*(qm*KMV[c16+kk] - 1.f);
      lreg[0*16+kk] += (S0 - mz*WZT[0])*rz + WZC[0] + bias;
      lreg[1*16+kk] += (S1 - mz*WZT[1])*rz + WZC[1] + bias;
      lreg[2*16+kk] += (S2 - mz*WZT[2])*rz + WZC[2] + bias;
      lreg[3*16+kk] += (S3 - mz*WZT[3])*rz + WZC[3] + bias;
    }
  }

  // ---------------- Phase 5: per-head softmax + PV ----------------
  float oreg[16];
  #pragma unroll
  for (int x=0;x<16;x++) oreg[x]=0.f;

  #pragma unroll
  for (int h=0;h<4;h++){
    { // softmax over ki (8 threads per row), write attn bf16 into H1
      float mx = lreg[h*16+0];
      #pragma unroll
      for (int kk=1;kk<16;kk++) mx = fmaxf(mx, lreg[h*16+kk]);
      mx = fmaxf(mx, __shfl_xor(mx,1,8));
      mx = fmaxf(mx, __shfl_xor(mx,2,8));
      mx = fmaxf(mx, __shfl_xor(mx,4,8));
      float ex[16]; float sme=0.f;
      #pragma unroll
      for (int kk=0;kk<16;kk++){ ex[kk]=__expf(lreg[h*16+kk]-mx); sme+=ex[kk]; }
      sme += __shfl_xor(sme,1,8);
      sme += __shfl_xor(sme,2,8);
      sme += __shfl_xor(sme,4,8);
      float inv = 1.f/sme;
      u16* ad = H1_BF + qi*136 + c16;
      ((uint2*)ad)[0] = make_uint2(pk2(ex[0]*inv,ex[1]*inv),  pk2(ex[2]*inv,ex[3]*inv));
      ((uint2*)ad)[1] = make_uint2(pk2(ex[4]*inv,ex[5]*inv),  pk2(ex[6]*inv,ex[7]*inv));
      ((uint2*)ad)[2] = make_uint2(pk2(ex[8]*inv,ex[9]*inv),  pk2(ex[10]*inv,ex[11]*inv));
      ((uint2*)ad)[3] = make_uint2(pk2(ex[12]*inv,ex[13]*inv),pk2(ex[14]*inv,ex[15]*inv));
    }
    { // stage vT_h into H2
      float va0[8], va1[8];
      #pragma unroll
      for (int x=0;x<8;x++){ va0[x]=0.f; va1[x]=0.f; }
      const u16* ar0 = A_BF + r2*136;
      const u16* ar1 = A_BF + (r2+1)*136;
      #pragma unroll 1
      for (int j0=0;j0<128;j0+=8){
        uint4 p0=*(const uint4*)(ar0+j0), p1=*(const uint4*)(ar1+j0);
        float a0[8],a1[8]; up8(p0,a0); up8(p1,a1);
        #pragma unroll
        for (int jj=0;jj<8;jj++)
          FMA8x2(va0, va1, Wv + (size_t)(j0+jj)*C_ + h*32 + cq8, a0[jj], a1[jj]);
      }
      #pragma unroll
      for (int c=0;c<8;c++){
        H2_BF[(cq8+c)*136 + r2]   = f2bf(va0[c]);
        H2_BF[(cq8+c)*136 + r2+1] = f2bf(va1[c]);
      }
    }
    __syncthreads();
    { // PV: oreg[h*4+jj] += attn[qi][:] . v[:][cg*4+jj]
      const int c4h = cg*4;
      const u16* arow2 = H1_BF + qi*136;
      #pragma unroll 1
      for (int kb=0;kb<16;kb++){
        uint4 ap = *(const uint4*)(arow2 + kb*8);
        float av[8]; up8(ap,av);
        #pragma unroll
        for (int jj=0;jj<4;jj++){
          uint4 vp = *(const uint4*)(H2_BF + (c4h+jj)*136 + kb*8);
          float vv[8]; up8(vp,vv);
          oreg[h*4+jj] += av[0]*vv[0]+av[1]*vv[1]+av[2]*vv[2]+av[3]*vv[3]
                        + av[4]*vv[4]+av[5]*vv[5]+av[6]*vv[6]+av[7]*vv[7];
        }
      }
    }
    __syncthreads();
  }

  // ---------------- Phase 6: g*o -> BQ (bf16); raw s_q -> SQF (f32) ----------------
  {
    u16* d = BQ_BF + qi*136;
    #pragma unroll
    for (int h=0;h<4;h++){
      float g0=gv[h*4+0]*oreg[h*4+0], g1=gv[h*4+1]*oreg[h*4+1];
      float g2=gv[h*4+2]*oreg[h*4+2], g3=gv[h*4+3]*oreg[h*4+3];
      *((uint2*)(d + h*32 + cg*4)) = make_uint2(pk2(g0,g1), pk2(g2,g3));
    }
    const float* srow = gs + ((size_t)b*N_ + (size_t)i*NQ_ + qi)*C_ + c16;
    float* sd = SQF + qi*136 + c16;
    #pragma unroll
    for (int t4=0;t4<4;t4++) *((float4*)(sd + t4*4)) = *(const float4*)(srow + t4*4);
  }
  __syncthreads();

  // ---------------- Phase 7: out = sigmoid(s@W_ado + b_ado) * ((g*o)@Wo + bo) ----------------
  {
    float wacc[16], dacc[16];
    #pragma unroll
    for (int x=0;x<16;x++){ wacc[x]=0.f; dacc[x]=0.f; }
    const u16* grow_ = BQ_BF + qi*136;
    const float* sqrow = SQF + qi*136;
    #pragma unroll 1
    for (int j0=0;j0<128;j0+=8){
      uint4 p = *(const uint4*)(grow_ + j0);
      float ov[8]; up8(p,ov);
      float4 s0 = *(const float4*)(sqrow + j0);
      float4 s1 = *(const float4*)(sqrow + j0 + 4);
      float sv[8] = {s0.x,s0.y,s0.z,s0.w, s1.x,s1.y,s1.z,s1.w};
      #pragma unroll
      for (int jj=0;jj<8;jj++){
        FMA16(wacc, Wo   + (size_t)(j0+jj)*C_ + c16, ov[jj]);
        FMA16(dacc, Wado + (size_t)(j0+jj)*C_ + c16, sv[jj]);
      }
    }
    float* orow = gout + ((size_t)b*N_ + (size_t)i*NQ_ + qi)*C_ + c16;
    #pragma unroll
    for (int t4=0;t4<4;t4++){
      float4 bo4 = *(const float4*)(bo   + c16 + t4*4);
      float4 bd4 = *(const float4*)(bado + c16 + t4*4);
      float4 r;
      r.x = sigm(dacc[t4*4+0]+bd4.x)*(wacc[t4*4+0]+bo4.x);
      r.y = sigm(dacc[t4*4+1]+bd4.y)*(wacc[t4*4+1]+bo4.y);
      r.z = sigm(dacc[t4*4+2]+bd4.z)*(wacc[t4*4+2]+bo4.z);
      r.w = sigm(dacc[t4*4+3]+bd4.w)*(wacc[t4*4+3]+bo4.w);
      *((float4*)(orow + t4*4)) = r;
    }
  }
}

extern "C" void kernel_launch(void* const* d_in, const int* in_sizes, int n_in,
                              void* d_out, int out_size, void* d_ws, size_t ws_size,
                              hipStream_t stream) {
  (void)in_sizes; (void)n_in; (void)d_ws; (void)ws_size; (void)out_size;
  dim3 grid(NB_, B_), block(256);
  capb_kernel<<<grid, block, 0, stream>>>(
    (const float*)d_in[0],  (const float*)d_in[1],  (const float*)d_in[2],  (const float*)d_in[3],
    (const float*)d_in[4],  (const float*)d_in[5],  (const float*)d_in[6],  (const float*)d_in[7],
    (const float*)d_in[8],  (const float*)d_in[9],  (const float*)d_in[10], (const float*)d_in[11],
    (const float*)d_in[12], (const float*)d_in[13], (const float*)d_in[14], (const float*)d_in[15],
    (const float*)d_in[16], (const float*)d_in[17], (const float*)d_in[18], (const float*)d_in[19],
    (const float*)d_in[20], (const float*)d_in[21], (const float*)d_in[22], (const float*)d_in[23],
    (float*)d_out);
}

// Round 2
// 551.849 us; speedup vs baseline: 3.4524x; 3.4524x over previous
//
#include <hip/hip_runtime.h>
#include <cstdint>
#include <cstddef>

#define B_ 4
#define N_ 8192
#define C_ 128
#define NB_ 256
#define EPS_ 1e-5f

typedef unsigned int u32;
typedef unsigned short u16;

typedef short bf16x8 __attribute__((ext_vector_type(8)));
typedef float f32x4 __attribute__((ext_vector_type(4)));
union U16x8 { uint4 u4; bf16x8 v; };

__device__ __forceinline__ float bf2f(u16 v){ union{u32 i; float f;} x; x.i = ((u32)v)<<16; return x.f; }
__device__ __forceinline__ u16 f2bf(float f){ union{float f; u32 i;} x; x.f=f; u32 r = x.i + 0x7fffu + ((x.i>>16)&1u); return (u16)(r>>16); }
__device__ __forceinline__ u32 pk2(float a, float b){ return (u32)f2bf(a) | ((u32)f2bf(b)<<16); }
__device__ __forceinline__ float sigm(float x){ return 1.f/(1.f+__expf(-x)); }

// ============================ k0: weight prep ============================
// PW: 10 mats, each packed for B-fragment consumption of mfma_f32_16x16x32_bf16:
//   elem index = (((mat*4 + ks)*8 + nt)*64 + lane)*8 + j
//   source W[k][n], k = ks*32 + (lane>>4)*8 + j, n = nt*16 + (lane&15)
// mats: 0 Wgq*lnsqw, 1 Wbq*lnsqw, 2 Wgk*lnskw, 3 Wbk*lnskw, 4 Wado,
//       5 Wq*scale, 6 Wg, 7 Wk, 8 Wv, 9 Wo
// AUX: [0..127] colsum(Wado); [128+h*16+c] lnzw[c]*Wz[c][h]; [192+h] sum_c lnzb[c]*Wz[c][h]
__global__ void k0_prep(const float* __restrict__ Wgq, const float* __restrict__ Wbq,
                        const float* __restrict__ Wgk, const float* __restrict__ Wbk,
                        const float* __restrict__ Wado, const float* __restrict__ Wq_,
                        const float* __restrict__ Wg_, const float* __restrict__ Wk_,
                        const float* __restrict__ Wv_, const float* __restrict__ Wo_,
                        const float* __restrict__ lnsqw, const float* __restrict__ lnskw,
                        const float* __restrict__ lnzw, const float* __restrict__ lnzb,
                        const float* __restrict__ Wz,
                        u16* __restrict__ PW, float* __restrict__ AUX)
{
  if (blockIdx.x < 80) {
    int gid = blockIdx.x*256 + threadIdx.x;     // 0..20479
    int mat = gid >> 11;
    int rem = gid & 2047;
    int ks = rem >> 9;
    int rem2 = rem & 511;
    int nt = rem2 >> 6;
    int lane = rem2 & 63;
    int kbase = ks*32 + (lane>>4)*8;
    int n = nt*16 + (lane&15);
    const float* W; int scmode = 0; float fixed = 1.f;
    switch (mat) {
      case 0: W = Wgq; scmode = 1; break;
      case 1: W = Wbq; scmode = 1; break;
      case 2: W = Wgk; scmode = 2; break;
      case 3: W = Wbk; scmode = 2; break;
      case 4: W = Wado; break;
      case 5: W = Wq_; fixed = 0.17677669529663687f; break;
      case 6: W = Wg_; break;
      case 7: W = Wk_; break;
      case 8: W = Wv_; break;
      default: W = Wo_; break;
    }
    u16 o[8];
    #pragma unroll
    for (int j=0;j<8;j++){
      int k = kbase + j;
      float sc = fixed;
      if (scmode == 1) sc *= lnsqw[k];
      else if (scmode == 2) sc *= lnskw[k];
      o[j] = f2bf(W[k*128 + n] * sc);
    }
    uint4 pk;
    pk.x = (u32)o[0] | ((u32)o[1]<<16); pk.y = (u32)o[2] | ((u32)o[3]<<16);
    pk.z = (u32)o[4] | ((u32)o[5]<<16); pk.w = (u32)o[6] | ((u32)o[7]<<16);
    *(uint4*)(PW + (size_t)gid*8) = pk;
  } else {
    int t = threadIdx.x;
    if (t < 128) {
      float s = 0.f;
      for (int k=0;k<128;k++) s += Wado[k*128 + t];
      AUX[t] = s;
    } else if (t < 192) {
      int h = (t-128) >> 4, c = (t-128) & 15;
      AUX[t] = lnzw[c] * Wz[c*4 + h];
    } else if (t < 196) {
      int h = t - 192;
      float s = 0.f;
      for (int c=0;c<16;c++) s += lnzb[c]*Wz[c*4 + h];
      AUX[t] = s;
    }
  }
}

// ============================ MFMA helpers ============================
__device__ __forceinline__ void mm_single(f32x4 acc[4][2], const u16* Abase, const u16* __restrict__ PW,
                                          int mat, int wave, int lane, int lq, int quad)
{
  #pragma unroll
  for (int ks=0; ks<4; ks++){
    U16x8 b0, b1;
    b0.u4 = *(const uint4*)(PW + (size_t)((((mat*4+ks)*8) + wave*2+0)*64 + lane)*8);
    b1.u4 = *(const uint4*)(PW + (size_t)((((mat*4+ks)*8) + wave*2+1)*64 + lane)*8);
    #pragma unroll
    for (int mt=0; mt<4; mt++){
      U16x8 a; a.u4 = *(const uint4*)(Abase + (mt*16+lq)*136 + ks*32 + quad*8);
      acc[mt][0] = __builtin_amdgcn_mfma_f32_16x16x32_bf16(a.v, b0.v, acc[mt][0], 0,0,0);
      acc[mt][1] = __builtin_amdgcn_mfma_f32_16x16x32_bf16(a.v, b1.v, acc[mt][1], 0,0,0);
    }
  }
}
__device__ __forceinline__ void mm_dual(f32x4 acc1[4][2], int m1, f32x4 acc2[4][2], int m2,
                                        const u16* Abase, const u16* __restrict__ PW,
                                        int wave, int lane, int lq, int quad)
{
  #pragma unroll
  for (int ks=0; ks<4; ks++){
    U16x8 b10, b11, b20, b21;
    b10.u4 = *(const uint4*)(PW + (size_t)((((m1*4+ks)*8) + wave*2+0)*64 + lane)*8);
    b11.u4 = *(const uint4*)(PW + (size_t)((((m1*4+ks)*8) + wave*2+1)*64 + lane)*8);
    b20.u4 = *(const uint4*)(PW + (size_t)((((m2*4+ks)*8) + wave*2+0)*64 + lane)*8);
    b21.u4 = *(const uint4*)(PW + (size_t)((((m2*4+ks)*8) + wave*2+1)*64 + lane)*8);
    #pragma unroll
    for (int mt=0; mt<4; mt++){
      U16x8 a; a.u4 = *(const uint4*)(Abase + (mt*16+lq)*136 + ks*32 + quad*8);
      acc1[mt][0] = __builtin_amdgcn_mfma_f32_16x16x32_bf16(a.v, b10.v, acc1[mt][0], 0,0,0);
      acc1[mt][1] = __builtin_amdgcn_mfma_f32_16x16x32_bf16(a.v, b11.v, acc1[mt][1], 0,0,0);
      acc2[mt][0] = __builtin_amdgcn_mfma_f32_16x16x32_bf16(a.v, b20.v, acc2[mt][0], 0,0,0);
      acc2[mt][1] = __builtin_amdgcn_mfma_f32_16x16x32_bf16(a.v, b21.v, acc2[mt][1], 0,0,0);
    }
  }
}
#define ZERO82(A) do{ _Pragma("unroll") for(int _m=0;_m<4;_m++){ A[_m][0]=(f32x4)(0.f); A[_m][1]=(f32x4)(0.f);} }while(0)

// ============================ k1: LN + 9-way projection GEMM ============================
// 64 rows per WG, 512 WGs. Writes Q,K [B*N][128] bf16; VT,GT [B][128][N] bf16; ADO [B*N][128] bf16.
__global__ __launch_bounds__(256, 2)
void k1_proj(const float* __restrict__ ga, const float* __restrict__ gs,
             const float* __restrict__ bgq, const float* __restrict__ bgk,
             const float* __restrict__ bg, const float* __restrict__ bado,
             const u16* __restrict__ PW, const float* __restrict__ AUX,
             u16* __restrict__ Q, u16* __restrict__ K, u16* __restrict__ VT,
             u16* __restrict__ GT, u16* __restrict__ ADO)
{
  __shared__ char arena[52736];
  u16* SN  = (u16*)arena;                 // [64][136] sn_hat, later AK
  u16* LNA = (u16*)(arena + 17408);       // [64][136] ln(a)
  u16* AQ  = (u16*)(arena + 34816);       // [64][136]
  float* SSTAT = (float*)(arena + 52224); // [64][2] (mean, std) of s rows

  const int tid = (int)threadIdx.x;
  const int rowbase = (int)blockIdx.x * 64;
  const int b = rowbase >> 13;
  const int nb0 = rowbase & 8191;
  const int wave = tid >> 6, lane = tid & 63;
  const int lq = lane & 15, quad = lane >> 4;

  // -------- phase 0: row LN stats, stage sn_hat + ln(a) --------
  {
    const float* sbase = gs + (size_t)rowbase*128;
    const float* abase = ga + (size_t)rowbase*128;
    #pragma unroll 1
    for (int t=0;t<8;t++){
      int chunk = t*256 + tid;
      int row = chunk >> 5;
      int k4 = (chunk & 31) * 4;
      float4 vs = *(const float4*)(sbase + (size_t)chunk*4);
      float4 va = *(const float4*)(abase + (size_t)chunk*4);
      float sm = vs.x+vs.y+vs.z+vs.w, sq = vs.x*vs.x+vs.y*vs.y+vs.z*vs.z+vs.w*vs.w;
      float am = va.x+va.y+va.z+va.w, a2 = va.x*va.x+va.y*va.y+va.z*va.z+va.w*va.w;
      #pragma unroll
      for (int m=1;m<32;m<<=1){
        sm += __shfl_xor(sm,m,32); sq += __shfl_xor(sq,m,32);
        am += __shfl_xor(am,m,32); a2 += __shfl_xor(a2,m,32);
      }
      float smean = sm*(1.f/128.f);
      float svar  = sq*(1.f/128.f) - smean*smean;
      float srstd = rsqrtf(svar + EPS_);
      float amean = am*(1.f/128.f);
      float avar  = a2*(1.f/128.f) - amean*amean;
      float arstd = rsqrtf(avar + EPS_);
      *(uint2*)(SN + row*136 + k4) = make_uint2(
        pk2((vs.x-smean)*srstd,(vs.y-smean)*srstd), pk2((vs.z-smean)*srstd,(vs.w-smean)*srstd));
      *(uint2*)(LNA + row*136 + k4) = make_uint2(
        pk2((va.x-amean)*arstd,(va.y-amean)*arstd), pk2((va.z-amean)*arstd,(va.w-amean)*arstd));
      if ((tid & 31) == 0){
        SSTAT[row*2]   = smean;
        SSTAT[row*2+1] = (svar + EPS_)*srstd;   // = sqrt(var+eps)
      }
    }
  }
  __syncthreads();

  const int cg0 = wave*32 + lq;
  const int cg1 = cg0 + 16;

  // -------- M_ado: ADO = sigmoid(std*(SN@Wado) + mean*colsum + b_ado) --------
  {
    f32x4 acc[4][2]; ZERO82(acc);
    mm_single(acc, SN, PW, 4, wave, lane, lq, quad);
    float cs0 = AUX[cg0], cs1 = AUX[cg1];
    float bb0 = bado[cg0], bb1 = bado[cg1];
    #pragma unroll
    for (int mt=0; mt<4; mt++){
      #pragma unroll
      for (int reg=0; reg<4; reg++){
        int row = mt*16 + quad*4 + reg;
        float mean = SSTAT[row*2], std = SSTAT[row*2+1];
        ADO[(size_t)(rowbase+row)*128 + cg0] = f2bf(sigm(std*acc[mt][0][reg] + mean*cs0 + bb0));
        ADO[(size_t)(rowbase+row)*128 + cg1] = f2bf(sigm(std*acc[mt][1][reg] + mean*cs1 + bb1));
      }
    }
  }

  // -------- M_gq + M_bq -> AQ = sigm(G+bgq)*ln(a) + B --------
  {
    f32x4 aG[4][2], aB[4][2]; ZERO82(aG); ZERO82(aB);
    mm_dual(aG, 0, aB, 1, SN, PW, wave, lane, lq, quad);
    float bq0 = bgq[cg0], bq1 = bgq[cg1];
    #pragma unroll
    for (int mt=0; mt<4; mt++){
      #pragma unroll
      for (int reg=0; reg<4; reg++){
        int row = mt*16 + quad*4 + reg;
        float l0 = bf2f(LNA[row*136 + cg0]), l1 = bf2f(LNA[row*136 + cg1]);
        AQ[row*136 + cg0] = f2bf(sigm(aG[mt][0][reg]+bq0)*l0 + aB[mt][0][reg]);
        AQ[row*136 + cg1] = f2bf(sigm(aG[mt][1][reg]+bq1)*l1 + aB[mt][1][reg]);
      }
    }
  }

  // -------- M_gk + M_bk -> AK (into SN buffer) --------
  {
    f32x4 aG[4][2], aB[4][2]; ZERO82(aG); ZERO82(aB);
    mm_dual(aG, 2, aB, 3, SN, PW, wave, lane, lq, quad);
    float bk0 = bgk[cg0], bk1 = bgk[cg1];
    #pragma unroll
    for (int mt=0; mt<4; mt++){
      #pragma unroll
      for (int reg=0; reg<4; reg++){
        int row = mt*16 + quad*4 + reg;
        float l0 = bf2f(LNA[row*136 + cg0]), l1 = bf2f(LNA[row*136 + cg1]);
        aG[mt][0][reg] = sigm(aG[mt][0][reg]+bk0)*l0 + aB[mt][0][reg];
        aG[mt][1][reg] = sigm(aG[mt][1][reg]+bk1)*l1 + aB[mt][1][reg];
      }
    }
    __syncthreads();   // all SN/AQ readers done
    #pragma unroll
    for (int mt=0; mt<4; mt++){
      #pragma unroll
      for (int reg=0; reg<4; reg++){
        int row = mt*16 + quad*4 + reg;
        SN[row*136 + cg0] = f2bf(aG[mt][0][reg]);
        SN[row*136 + cg1] = f2bf(aG[mt][1][reg]);
      }
    }
    __syncthreads();   // AK visible
  }

  // -------- M_q + M_g (A = AQ): write Q (scaled already), GT = sigmoid(..+bg) --------
  {
    f32x4 aQ_[4][2], aG_[4][2]; ZERO82(aQ_); ZERO82(aG_);
    mm_dual(aQ_, 5, aG_, 6, AQ, PW, wave, lane, lq, quad);
    float bg0 = bg[cg0], bg1 = bg[cg1];
    #pragma unroll
    for (int mt=0; mt<4; mt++){
      #pragma unroll
      for (int reg=0; reg<4; reg++){
        int row = mt*16 + quad*4 + reg;
        Q[(size_t)(rowbase+row)*128 + cg0] = f2bf(aQ_[mt][0][reg]);
        Q[(size_t)(rowbase+row)*128 + cg1] = f2bf(aQ_[mt][1][reg]);
      }
      ushort4 p0, p1;
      p0.x = f2bf(sigm(aG_[mt][0][0]+bg0)); p0.y = f2bf(sigm(aG_[mt][0][1]+bg0));
      p0.z = f2bf(sigm(aG_[mt][0][2]+bg0)); p0.w = f2bf(sigm(aG_[mt][0][3]+bg0));
      p1.x = f2bf(sigm(aG_[mt][1][0]+bg1)); p1.y = f2bf(sigm(aG_[mt][1][1]+bg1));
      p1.z = f2bf(sigm(aG_[mt][1][2]+bg1)); p1.w = f2bf(sigm(aG_[mt][1][3]+bg1));
      int nloc = nb0 + mt*16 + quad*4;
      *(ushort4*)(GT + ((size_t)(b*128 + cg0))*N_ + nloc) = p0;
      *(ushort4*)(GT + ((size_t)(b*128 + cg1))*N_ + nloc) = p1;
    }
  }

  // -------- M_k + M_v (A = AK in SN): write K row-major, VT transposed --------
  {
    f32x4 aK_[4][2], aV_[4][2]; ZERO82(aK_); ZERO82(aV_);
    mm_dual(aK_, 7, aV_, 8, SN, PW, wave, lane, lq, quad);
    #pragma unroll
    for (int mt=0; mt<4; mt++){
      #pragma unroll
      for (int reg=0; reg<4; reg++){
        int row = mt*16 + quad*4 + reg;
        K[(size_t)(rowbase+row)*128 + cg0] = f2bf(aK_[mt][0][reg]);
        K[(size_t)(rowbase+row)*128 + cg1] = f2bf(aK_[mt][1][reg]);
      }
      ushort4 p0, p1;
      p0.x = f2bf(aV_[mt][0][0]); p0.y = f2bf(aV_[mt][0][1]);
      p0.z = f2bf(aV_[mt][0][2]); p0.w = f2bf(aV_[mt][0][3]);
      p1.x = f2bf(aV_[mt][1][0]); p1.y = f2bf(aV_[mt][1][1]);
      p1.z = f2bf(aV_[mt][1][2]); p1.w = f2bf(aV_[mt][1][3]);
      int nloc = nb0 + mt*16 + quad*4;
      *(ushort4*)(VT + ((size_t)(b*128 + cg0))*N_ + nloc) = p0;
      *(ushort4*)(VT + ((size_t)(b*128 + cg1))*N_ + nloc) = p1;
    }
  }
}

// ============================ k2: windowed attention ============================
// grid (256, 4); wave h owns head h. 1 WG = one (b, window).
__global__ __launch_bounds__(256, 3)
void k2_attn(const float* __restrict__ gz, const float* __restrict__ gmask,
             const float* __restrict__ bo,
             const u16* __restrict__ PW, const float* __restrict__ AUX,
             const u16* __restrict__ Q, const u16* __restrict__ K,
             const u16* __restrict__ VT, const u16* __restrict__ GT,
             const u16* __restrict__ ADO, float* __restrict__ gout)
{
  __shared__ char arena[44160];
  u16* ATTall = (u16*)arena;             // 4 x [32][136] bf16, per-wave
  u16* GO     = (u16*)(arena + 34816);   // [32][136] bf16 (g*o, q-major)
  float* KMV  = (float*)(arena + 43520); // [128]
  float* QM   = (float*)(arena + 44032); // [32]

  const int i = (int)blockIdx.x, b = (int)blockIdx.y;
  const int tid = (int)threadIdx.x;
  const int wave = tid >> 6, lane = tid & 63;
  const int lq = lane & 15, quad = lane >> 4;
  const int h = wave;
  const int start = i*32 - 48;
  u16* ATT = ATTall + h*(32*136);

  if (tid < 128) {
    int raw = start + tid;
    int g = min(max(raw,0), N_-1);
    KMV[tid] = ((raw >= 0 && raw < N_) ? 1.f : 0.f) * gmask[(size_t)b*N_ + g];
  } else if (tid < 160) {
    QM[tid-128] = gmask[(size_t)b*N_ + i*32 + (tid-128)];
  }
  __syncthreads();

  // -------- logits: L[mt][nt] = Q_h @ K_h^T --------
  f32x4 L[2][8];
  #pragma unroll
  for (int mt=0;mt<2;mt++) for (int nt=0;nt<8;nt++) L[mt][nt] = (f32x4)(0.f);
  {
    U16x8 aQ[2];
    #pragma unroll
    for (int mt=0;mt<2;mt++)
      aQ[mt].u4 = *(const uint4*)(Q + ((size_t)b*N_ + i*32 + mt*16 + lq)*128 + h*32 + quad*8);
    #pragma unroll
    for (int nt=0;nt<8;nt++){
      int kr = min(max(start + nt*16 + lq, 0), N_-1);
      U16x8 bk; bk.u4 = *(const uint4*)(K + ((size_t)b*N_ + kr)*128 + h*32 + quad*8);
      L[0][nt] = __builtin_amdgcn_mfma_f32_16x16x32_bf16(aQ[0].v, bk.v, L[0][nt], 0,0,0);
      L[1][nt] = __builtin_amdgcn_mfma_f32_16x16x32_bf16(aQ[1].v, bk.v, L[1][nt], 0,0,0);
    }
  }

  // -------- z pair-bias (stream z once) + mask bias --------
  {
    float wz[16]; float wzt = 0.f;
    #pragma unroll
    for (int c=0;c<16;c++){ wz[c] = AUX[128 + h*16 + c]; wzt += wz[c]; }
    float wzc = AUX[192 + h];
    float kmvv[8];
    #pragma unroll
    for (int nt=0;nt<8;nt++) kmvv[nt] = KMV[nt*16 + lq];
    const float* zb0 = gz + (size_t)(b*NB_ + i)*32*128*16;
    #pragma unroll
    for (int mt=0;mt<2;mt++){
      #pragma unroll 1
      for (int reg=0;reg<4;reg++){
        int q = mt*16 + quad*4 + reg;
        float qm = QM[q];
        const float* zq = zb0 + (size_t)q*128*16 + lq*16;
        #pragma unroll 2
        for (int nt=0;nt<8;nt++){
          const float* zp = zq + nt*16*16;
          float4 z0 = *(const float4*)(zp);
          float4 z1 = *(const float4*)(zp+4);
          float4 z2 = *(const float4*)(zp+8);
          float4 z3 = *(const float4*)(zp+12);
          float zv[16] = {z0.x,z0.y,z0.z,z0.w, z1.x,z1.y,z1.z,z1.w,
                          z2.x,z2.y,z2.z,z2.w, z3.x,z3.y,z3.z,z3.w};
          float sm=0.f, sq=0.f, S=0.f;
          #pragma unroll
          for (int c=0;c<16;c++){ sm += zv[c]; sq = fmaf(zv[c],zv[c],sq); S = fmaf(zv[c],wz[c],S); }
          float mz = sm*(1.f/16.f);
          float rz = rsqrtf(sq*(1.f/16.f) - mz*mz + EPS_);
          float bias = 1000000000.0f*(qm*kmvv[nt] - 1.f);
          L[mt][nt][reg] += (S - mz*wzt)*rz + wzc + bias;
        }
      }
    }
  }

  // -------- softmax rows, write attn bf16 into per-wave ATT --------
  #pragma unroll
  for (int mt=0;mt<2;mt++){
    #pragma unroll
    for (int reg=0;reg<4;reg++){
      float mx = -3.0e38f;
      #pragma unroll
      for (int nt=0;nt<8;nt++) mx = fmaxf(mx, L[mt][nt][reg]);
      mx = fmaxf(mx, __shfl_xor(mx,1,16));
      mx = fmaxf(mx, __shfl_xor(mx,2,16));
      mx = fmaxf(mx, __shfl_xor(mx,4,16));
      mx = fmaxf(mx, __shfl_xor(mx,8,16));
      float e[8]; float s = 0.f;
      #pragma unroll
      for (int nt=0;nt<8;nt++){ e[nt] = __expf(L[mt][nt][reg]-mx); s += e[nt]; }
      s += __shfl_xor(s,1,16);
      s += __shfl_xor(s,2,16);
      s += __shfl_xor(s,4,16);
      s += __shfl_xor(s,8,16);
      float inv = 1.f/s;
      int q = mt*16 + quad*4 + reg;
      #pragma unroll
      for (int nt=0;nt<8;nt++) ATT[q*136 + nt*16 + lq] = f2bf(e[nt]*inv);
    }
  }

  // -------- o^T = V_h^T @ attn^T --------
  f32x4 O[2][2];
  O[0][0]=(f32x4)(0.f); O[0][1]=(f32x4)(0.f); O[1][0]=(f32x4)(0.f); O[1][1]=(f32x4)(0.f);
  #pragma unroll
  for (int ks=0;ks<4;ks++){
    U16x8 ba[2];
    #pragma unroll
    for (int nt=0;nt<2;nt++)
      ba[nt].u4 = *(const uint4*)(ATT + (nt*16+lq)*136 + ks*32 + quad*8);
    int kk = start + ks*32 + quad*8;
    kk = min(max(kk,0), N_-8);   // chunk-aligned (start % 16 == 0) -> safe
    #pragma unroll
    for (int mt=0;mt<2;mt++){
      U16x8 av;
      av.u4 = *(const uint4*)(VT + ((size_t)(b*128 + h*32 + mt*16 + lq))*N_ + kk);
      O[mt][0] = __builtin_amdgcn_mfma_f32_16x16x32_bf16(av.v, ba[0].v, O[mt][0], 0,0,0);
      O[mt][1] = __builtin_amdgcn_mfma_f32_16x16x32_bf16(av.v, ba[1].v, O[mt][1], 0,0,0);
    }
  }

  // -------- gate, write (g*o) into GO [q][128] --------
  #pragma unroll
  for (int mt=0;mt<2;mt++){
    #pragma unroll
    for (int nt=0;nt<2;nt++){
      int q = nt*16 + lq;
      int cb = h*32 + mt*16 + quad*4;
      float g0 = bf2f(GT[((size_t)(b*128 + cb+0))*N_ + i*32 + q]);
      float g1 = bf2f(GT[((size_t)(b*128 + cb+1))*N_ + i*32 + q]);
      float g2 = bf2f(GT[((size_t)(b*128 + cb+2))*N_ + i*32 + q]);
      float g3 = bf2f(GT[((size_t)(b*128 + cb+3))*N_ + i*32 + q]);
      ushort4 p;
      p.x = f2bf(g0*O[mt][nt][0]); p.y = f2bf(g1*O[mt][nt][1]);
      p.z = f2bf(g2*O[mt][nt][2]); p.w = f2bf(g3*O[mt][nt][3]);
      *(ushort4*)(GO + q*136 + cb) = p;
    }
  }
  __syncthreads();

  // -------- out = sigmoid(ado) * (GO @ Wo + bo) --------
  {
    f32x4 U[2][2];
    U[0][0]=(f32x4)(0.f); U[0][1]=(f32x4)(0.f); U[1][0]=(f32x4)(0.f); U[1][1]=(f32x4)(0.f);
    #pragma unroll
    for (int ks=0;ks<4;ks++){
      U16x8 b0, b1;
      b0.u4 = *(const uint4*)(PW + (size_t)((((9*4+ks)*8) + wave*2+0)*64 + lane)*8);
      b1.u4 = *(const uint4*)(PW + (size_t)((((9*4+ks)*8) + wave*2+1)*64 + lane)*8);
      #pragma unroll
      for (int mt=0;mt<2;mt++){
        U16x8 a; a.u4 = *(const uint4*)(GO + (mt*16+lq)*136 + ks*32 + quad*8);
        U[mt][0] = __builtin_amdgcn_mfma_f32_16x16x32_bf16(a.v, b0.v, U[mt][0], 0,0,0);
        U[mt][1] = __builtin_amdgcn_mfma_f32_16x16x32_bf16(a.v, b1.v, U[mt][1], 0,0,0);
      }
    }
    const int cg0 = wave*32 + lq, cg1 = cg0 + 16;
    float b00 = bo[cg0], b01 = bo[cg1];
    #pragma unroll
    for (int mt=0;mt<2;mt++){
      #pragma unroll
      for (int reg=0;reg<4;reg++){
        int q = mt*16 + quad*4 + reg;
        size_t rowoff = ((size_t)b*N_ + i*32 + q)*128;
        float ad0 = bf2f(ADO[rowoff + cg0]);
        float ad1 = bf2f(ADO[rowoff + cg1]);
        gout[rowoff + cg0] = ad0*(U[mt][0][reg] + b00);
        gout[rowoff + cg1] = ad1*(U[mt][1][reg] + b01);
      }
    }
  }
}

// ============================ launch ============================
extern "C" void kernel_launch(void* const* d_in, const int* in_sizes, int n_in,
                              void* d_out, int out_size, void* d_ws, size_t ws_size,
                              hipStream_t stream) {
  (void)in_sizes; (void)n_in; (void)out_size; (void)ws_size;
  const float* ga    = (const float*)d_in[0];
  const float* gz    = (const float*)d_in[1];
  const float* gs    = (const float*)d_in[2];
  const float* gmask = (const float*)d_in[3];
  const float* lnsqw = (const float*)d_in[4];
  const float* Wgq   = (const float*)d_in[5];
  const float* bgq   = (const float*)d_in[6];
  const float* Wbq   = (const float*)d_in[7];
  const float* lnskw = (const float*)d_in[8];
  const float* Wgk   = (const float*)d_in[9];
  const float* bgk   = (const float*)d_in[10];
  const float* Wbk   = (const float*)d_in[11];
  const float* lnzw  = (const float*)d_in[12];
  const float* lnzb  = (const float*)d_in[13];
  const float* Wz    = (const float*)d_in[14];
  const float* Wq    = (const float*)d_in[15];
  const float* Wk    = (const float*)d_in[16];
  const float* Wv    = (const float*)d_in[17];
  const float* Wg    = (const float*)d_in[18];
  const float* bg    = (const float*)d_in[19];
  const float* Wo    = (const float*)d_in[20];
  const float* bo    = (const float*)d_in[21];
  const float* Wado  = (const float*)d_in[22];
  const float* bado  = (const float*)d_in[23];

  char* ws = (char*)d_ws;
  u16* Qb  = (u16*)(ws + 0);
  u16* Kb  = (u16*)(ws + 8388608);
  u16* VTb = (u16*)(ws + 16777216);
  u16* GTb = (u16*)(ws + 25165824);
  u16* ADOb= (u16*)(ws + 33554432);
  u16* PW  = (u16*)(ws + 41943040);
  float* AUX = (float*)(ws + 41943040 + 327680);

  k0_prep<<<81, 256, 0, stream>>>(Wgq, Wbq, Wgk, Wbk, Wado, Wq, Wg, Wk, Wv, Wo,
                                  lnsqw, lnskw, lnzw, lnzb, Wz, PW, AUX);
  k1_proj<<<512, 256, 0, stream>>>(ga, gs, bgq, bgk, bg, bado, PW, AUX,
                                   Qb, Kb, VTb, GTb, ADOb);
  k2_attn<<<dim3(NB_, B_), 256, 0, stream>>>(gz, gmask, bo, PW, AUX,
                                             Qb, Kb, VTb, GTb, ADOb, (float*)d_out);
}

// Round 3
// 463.728 us; speedup vs baseline: 4.1085x; 1.1900x over previous
//
#include <hip/hip_runtime.h>
#include <cstdint>
#include <cstddef>

#define B_ 4
#define N_ 8192
#define C_ 128
#define NB_ 256
#define EPS_ 1e-5f

typedef unsigned int u32;
typedef unsigned short u16;

typedef short bf16x8 __attribute__((ext_vector_type(8)));
typedef float f32x4 __attribute__((ext_vector_type(4)));
union U16x8 { uint4 u4; bf16x8 v; };

__device__ __forceinline__ float bf2f(u16 v){ union{u32 i; float f;} x; x.i = ((u32)v)<<16; return x.f; }
__device__ __forceinline__ u16 f2bf(float f){ union{float f; u32 i;} x; x.f=f; u32 r = x.i + 0x7fffu + ((x.i>>16)&1u); return (u16)(r>>16); }
__device__ __forceinline__ u32 pk2(float a, float b){ return (u32)f2bf(a) | ((u32)f2bf(b)<<16); }
__device__ __forceinline__ float sigm(float x){ return 1.f/(1.f+__expf(-x)); }

// ============================ k0: weight prep (blocks 0..80) + z-bias stream (blocks 81..) ============================
// PW packing (B-fragment order for mfma_f32_16x16x32_bf16):
//   elem index = (((mat*4 + ks)*8 + nt)*64 + lane)*8 + j ;  W[k][n], k = ks*32+(lane>>4)*8+j, n = nt*16+(lane&15)
// mats: 0 Wgq*lnsqw, 1 Wbq*lnsqw, 2 Wgk*lnskw, 3 Wbk*lnskw, 4 Wado, 5 Wq*scale, 6 Wg, 7 Wk, 8 Wv, 9 Wo
// AUX: [0..127] colsum(Wado)
// ZB[b][i][h][key(128)][q(32)] bf16 = pair-bias (LN(z)@Wz per head) + 1e9*(qmask*kmask*valid - 1)
__global__ void k0_prep(const float* __restrict__ Wgq, const float* __restrict__ Wbq,
                        const float* __restrict__ Wgk, const float* __restrict__ Wbk,
                        const float* __restrict__ Wado, const float* __restrict__ Wq_,
                        const float* __restrict__ Wg_, const float* __restrict__ Wk_,
                        const float* __restrict__ Wv_, const float* __restrict__ Wo_,
                        const float* __restrict__ lnsqw, const float* __restrict__ lnskw,
                        const float* __restrict__ lnzw, const float* __restrict__ lnzb,
                        const float* __restrict__ Wz,
                        const float* __restrict__ gz, const float* __restrict__ gmask,
                        u16* __restrict__ PW, float* __restrict__ AUX, u16* __restrict__ ZB)
{
  __shared__ float WZL[72];  // [c*4+h] = lnzw[c]*Wz[c][h]; [64+h]=sum_c lnzw*Wz; [68+h]=sum_c lnzb*Wz
  if (blockIdx.x < 81) {
    if (blockIdx.x < 80) {
      int gid = blockIdx.x*256 + threadIdx.x;     // 0..20479
      int mat = gid >> 11;
      int rem = gid & 2047;
      int ks = rem >> 9;
      int rem2 = rem & 511;
      int nt = rem2 >> 6;
      int lane = rem2 & 63;
      int kbase = ks*32 + (lane>>4)*8;
      int n = nt*16 + (lane&15);
      const float* W; int scmode = 0; float fixed = 1.f;
      switch (mat) {
        case 0: W = Wgq; scmode = 1; break;
        case 1: W = Wbq; scmode = 1; break;
        case 2: W = Wgk; scmode = 2; break;
        case 3: W = Wbk; scmode = 2; break;
        case 4: W = Wado; break;
        case 5: W = Wq_; fixed = 0.17677669529663687f; break;
        case 6: W = Wg_; break;
        case 7: W = Wk_; break;
        case 8: W = Wv_; break;
        default: W = Wo_; break;
      }
      u16 o[8];
      #pragma unroll
      for (int j=0;j<8;j++){
        int k = kbase + j;
        float sc = fixed;
        if (scmode == 1) sc *= lnsqw[k];
        else if (scmode == 2) sc *= lnskw[k];
        o[j] = f2bf(W[k*128 + n] * sc);
      }
      uint4 pk;
      pk.x = (u32)o[0] | ((u32)o[1]<<16); pk.y = (u32)o[2] | ((u32)o[3]<<16);
      pk.z = (u32)o[4] | ((u32)o[5]<<16); pk.w = (u32)o[6] | ((u32)o[7]<<16);
      *(uint4*)(PW + (size_t)gid*8) = pk;
    } else {
      int t = threadIdx.x;
      if (t < 128) {
        float s = 0.f;
        for (int k=0;k<128;k++) s += Wado[k*128 + t];
        AUX[t] = s;
      }
    }
    return;
  }

  // ---- z-bias streaming part ----
  {
    int t = (int)threadIdx.x;
    if (t < 64) WZL[t] = lnzw[t>>2] * Wz[t];
    else if (t < 68) { int h = t-64; float s=0.f; for (int c=0;c<16;c++) s += lnzw[c]*Wz[c*4+h]; WZL[64+h]=s; }
    else if (t < 72) { int h = t-68; float s=0.f; for (int c=0;c<16;c++) s += lnzb[c]*Wz[c*4+h]; WZL[68+h]=s; }
  }
  __syncthreads();

  const int blk = (int)blockIdx.x - 81;   // 0..8191
  const int bi = blk >> 3;                // b*256 + i
  const int kg = blk & 7;
  const int b = bi >> 8, i = bi & 255;
  const int t = (int)threadIdx.x;
  const int q = t & 31, kl = t >> 5;      // kl 0..7
  const int key0 = kg*16 + kl, key1 = key0 + 8;

  const float* z0 = gz + (size_t)bi*65536 + ((size_t)q*128 + key0)*16;
  const float* z1 = z0 + 8*16;
  float4 a0 = *(const float4*)(z0);      float4 a1 = *(const float4*)(z0+4);
  float4 a2 = *(const float4*)(z0+8);    float4 a3 = *(const float4*)(z0+12);
  float4 c0 = *(const float4*)(z1);      float4 c1 = *(const float4*)(z1+4);
  float4 c2 = *(const float4*)(z1+8);    float4 c3 = *(const float4*)(z1+12);

  const float qm = gmask[(size_t)b*N_ + i*32 + q];
  int raw0 = i*32 - 48 + key0;
  int raw1 = i*32 - 48 + key1;
  float km0 = (raw0 >= 0 && raw0 < N_) ? gmask[(size_t)b*N_ + raw0] : 0.f;
  float km1 = (raw1 >= 0 && raw1 < N_) ? gmask[(size_t)b*N_ + raw1] : 0.f;
  float mb0 = 1000000000.0f*(qm*km0 - 1.f);
  float mb1 = 1000000000.0f*(qm*km1 - 1.f);

  u16* zbase = ZB + (size_t)bi*16384 + q;
  #pragma unroll
  for (int p=0;p<2;p++){
    float zv[16];
    if (p==0){ zv[0]=a0.x;zv[1]=a0.y;zv[2]=a0.z;zv[3]=a0.w; zv[4]=a1.x;zv[5]=a1.y;zv[6]=a1.z;zv[7]=a1.w;
               zv[8]=a2.x;zv[9]=a2.y;zv[10]=a2.z;zv[11]=a2.w; zv[12]=a3.x;zv[13]=a3.y;zv[14]=a3.z;zv[15]=a3.w; }
    else     { zv[0]=c0.x;zv[1]=c0.y;zv[2]=c0.z;zv[3]=c0.w; zv[4]=c1.x;zv[5]=c1.y;zv[6]=c1.z;zv[7]=c1.w;
               zv[8]=c2.x;zv[9]=c2.y;zv[10]=c2.z;zv[11]=c2.w; zv[12]=c3.x;zv[13]=c3.y;zv[14]=c3.z;zv[15]=c3.w; }
    float sm=0.f, sq=0.f, S0=0.f, S1=0.f, S2=0.f, S3=0.f;
    #pragma unroll
    for (int c=0;c<16;c++){
      sm += zv[c]; sq = fmaf(zv[c],zv[c],sq);
      S0 = fmaf(zv[c], WZL[c*4+0], S0); S1 = fmaf(zv[c], WZL[c*4+1], S1);
      S2 = fmaf(zv[c], WZL[c*4+2], S2); S3 = fmaf(zv[c], WZL[c*4+3], S3);
    }
    float mz = sm*(1.f/16.f);
    float rz = rsqrtf(sq*(1.f/16.f) - mz*mz + EPS_);
    float mb = p ? mb1 : mb0;
    int key = p ? key1 : key0;
    u16* zo = zbase + key*32;
    zo[0*4096] = f2bf((S0 - mz*WZL[64])*rz + WZL[68] + mb);
    zo[1*4096] = f2bf((S1 - mz*WZL[65])*rz + WZL[69] + mb);
    zo[2*4096] = f2bf((S2 - mz*WZL[66])*rz + WZL[70] + mb);
    zo[3*4096] = f2bf((S3 - mz*WZL[67])*rz + WZL[71] + mb);
  }
}

// ============================ MFMA helpers ============================
__device__ __forceinline__ void mm_single(f32x4 acc[4][2], const u16* Abase, const u16* __restrict__ PW,
                                          int mat, int wave, int lane, int lq, int quad)
{
  #pragma unroll
  for (int ks=0; ks<4; ks++){
    U16x8 b0, b1;
    b0.u4 = *(const uint4*)(PW + (size_t)((((mat*4+ks)*8) + wave*2+0)*64 + lane)*8);
    b1.u4 = *(const uint4*)(PW + (size_t)((((mat*4+ks)*8) + wave*2+1)*64 + lane)*8);
    #pragma unroll
    for (int mt=0; mt<4; mt++){
      U16x8 a; a.u4 = *(const uint4*)(Abase + (mt*16+lq)*136 + ks*32 + quad*8);
      acc[mt][0] = __builtin_amdgcn_mfma_f32_16x16x32_bf16(a.v, b0.v, acc[mt][0], 0,0,0);
      acc[mt][1] = __builtin_amdgcn_mfma_f32_16x16x32_bf16(a.v, b1.v, acc[mt][1], 0,0,0);
    }
  }
}
__device__ __forceinline__ void mm_dual(f32x4 acc1[4][2], int m1, f32x4 acc2[4][2], int m2,
                                        const u16* Abase, const u16* __restrict__ PW,
                                        int wave, int lane, int lq, int quad)
{
  #pragma unroll
  for (int ks=0; ks<4; ks++){
    U16x8 b10, b11, b20, b21;
    b10.u4 = *(const uint4*)(PW + (size_t)((((m1*4+ks)*8) + wave*2+0)*64 + lane)*8);
    b11.u4 = *(const uint4*)(PW + (size_t)((((m1*4+ks)*8) + wave*2+1)*64 + lane)*8);
    b20.u4 = *(const uint4*)(PW + (size_t)((((m2*4+ks)*8) + wave*2+0)*64 + lane)*8);
    b21.u4 = *(const uint4*)(PW + (size_t)((((m2*4+ks)*8) + wave*2+1)*64 + lane)*8);
    #pragma unroll
    for (int mt=0; mt<4; mt++){
      U16x8 a; a.u4 = *(const uint4*)(Abase + (mt*16+lq)*136 + ks*32 + quad*8);
      acc1[mt][0] = __builtin_amdgcn_mfma_f32_16x16x32_bf16(a.v, b10.v, acc1[mt][0], 0,0,0);
      acc1[mt][1] = __builtin_amdgcn_mfma_f32_16x16x32_bf16(a.v, b11.v, acc1[mt][1], 0,0,0);
      acc2[mt][0] = __builtin_amdgcn_mfma_f32_16x16x32_bf16(a.v, b20.v, acc2[mt][0], 0,0,0);
      acc2[mt][1] = __builtin_amdgcn_mfma_f32_16x16x32_bf16(a.v, b21.v, acc2[mt][1], 0,0,0);
    }
  }
}
#define ZERO82(A) do{ _Pragma("unroll") for(int _m=0;_m<4;_m++){ A[_m][0]=(f32x4)(0.f); A[_m][1]=(f32x4)(0.f);} }while(0)

// ============================ k1: LN + 9-way projection GEMM ============================
// 64 rows per WG, 512 WGs. Q,K,G,ADO row-major [B*N][128] bf16; VT [B][128][N] bf16.
__global__ __launch_bounds__(256, 2)
void k1_proj(const float* __restrict__ ga, const float* __restrict__ gs,
             const float* __restrict__ bgq, const float* __restrict__ bgk,
             const float* __restrict__ bg, const float* __restrict__ bado,
             const u16* __restrict__ PW, const float* __restrict__ AUX,
             u16* __restrict__ Q, u16* __restrict__ K, u16* __restrict__ VT,
             u16* __restrict__ G, u16* __restrict__ ADO)
{
  __shared__ char arena[52736];
  u16* SN  = (u16*)arena;                 // [64][136] sn_hat, later AK
  u16* LNA = (u16*)(arena + 17408);       // [64][136] ln(a)
  u16* AQ  = (u16*)(arena + 34816);       // [64][136]
  float* SSTAT = (float*)(arena + 52224); // [64][2] (mean, std)

  const int tid = (int)threadIdx.x;
  const int rowbase = (int)blockIdx.x * 64;
  const int b = rowbase >> 13;
  const int nb0 = rowbase & 8191;
  const int wave = tid >> 6, lane = tid & 63;
  const int lq = lane & 15, quad = lane >> 4;

  {
    const float* sbase = gs + (size_t)rowbase*128;
    const float* abase = ga + (size_t)rowbase*128;
    #pragma unroll 1
    for (int t=0;t<8;t++){
      int chunk = t*256 + tid;
      int row = chunk >> 5;
      int k4 = (chunk & 31) * 4;
      float4 vs = *(const float4*)(sbase + (size_t)chunk*4);
      float4 va = *(const float4*)(abase + (size_t)chunk*4);
      float sm = vs.x+vs.y+vs.z+vs.w, sq = vs.x*vs.x+vs.y*vs.y+vs.z*vs.z+vs.w*vs.w;
      float am = va.x+va.y+va.z+va.w, a2 = va.x*va.x+va.y*va.y+va.z*va.z+va.w*va.w;
      #pragma unroll
      for (int m=1;m<32;m<<=1){
        sm += __shfl_xor(sm,m,32); sq += __shfl_xor(sq,m,32);
        am += __shfl_xor(am,m,32); a2 += __shfl_xor(a2,m,32);
      }
      float smean = sm*(1.f/128.f);
      float svar  = sq*(1.f/128.f) - smean*smean;
      float srstd = rsqrtf(svar + EPS_);
      float amean = am*(1.f/128.f);
      float avar  = a2*(1.f/128.f) - amean*amean;
      float arstd = rsqrtf(avar + EPS_);
      *(uint2*)(SN + row*136 + k4) = make_uint2(
        pk2((vs.x-smean)*srstd,(vs.y-smean)*srstd), pk2((vs.z-smean)*srstd,(vs.w-smean)*srstd));
      *(uint2*)(LNA + row*136 + k4) = make_uint2(
        pk2((va.x-amean)*arstd,(va.y-amean)*arstd), pk2((va.z-amean)*arstd,(va.w-amean)*arstd));
      if ((tid & 31) == 0){
        SSTAT[row*2]   = smean;
        SSTAT[row*2+1] = (svar + EPS_)*srstd;   // sqrt(var+eps)
      }
    }
  }
  __syncthreads();

  const int cg0 = wave*32 + lq;
  const int cg1 = cg0 + 16;

  // ADO
  {
    f32x4 acc[4][2]; ZERO82(acc);
    mm_single(acc, SN, PW, 4, wave, lane, lq, quad);
    float cs0 = AUX[cg0], cs1 = AUX[cg1];
    float bb0 = bado[cg0], bb1 = bado[cg1];
    #pragma unroll
    for (int mt=0; mt<4; mt++){
      #pragma unroll
      for (int reg=0; reg<4; reg++){
        int row = mt*16 + quad*4 + reg;
        float mean = SSTAT[row*2], std = SSTAT[row*2+1];
        ADO[(size_t)(rowbase+row)*128 + cg0] = f2bf(sigm(std*acc[mt][0][reg] + mean*cs0 + bb0));
        ADO[(size_t)(rowbase+row)*128 + cg1] = f2bf(sigm(std*acc[mt][1][reg] + mean*cs1 + bb1));
      }
    }
  }

  // AQ
  {
    f32x4 aG[4][2], aB[4][2]; ZERO82(aG); ZERO82(aB);
    mm_dual(aG, 0, aB, 1, SN, PW, wave, lane, lq, quad);
    float bq0 = bgq[cg0], bq1 = bgq[cg1];
    #pragma unroll
    for (int mt=0; mt<4; mt++){
      #pragma unroll
      for (int reg=0; reg<4; reg++){
        int row = mt*16 + quad*4 + reg;
        float l0 = bf2f(LNA[row*136 + cg0]), l1 = bf2f(LNA[row*136 + cg1]);
        AQ[row*136 + cg0] = f2bf(sigm(aG[mt][0][reg]+bq0)*l0 + aB[mt][0][reg]);
        AQ[row*136 + cg1] = f2bf(sigm(aG[mt][1][reg]+bq1)*l1 + aB[mt][1][reg]);
      }
    }
  }

  // AK (into SN)
  {
    f32x4 aG[4][2], aB[4][2]; ZERO82(aG); ZERO82(aB);
    mm_dual(aG, 2, aB, 3, SN, PW, wave, lane, lq, quad);
    float bk0 = bgk[cg0], bk1 = bgk[cg1];
    #pragma unroll
    for (int mt=0; mt<4; mt++){
      #pragma unroll
      for (int reg=0; reg<4; reg++){
        int row = mt*16 + quad*4 + reg;
        float l0 = bf2f(LNA[row*136 + cg0]), l1 = bf2f(LNA[row*136 + cg1]);
        aG[mt][0][reg] = sigm(aG[mt][0][reg]+bk0)*l0 + aB[mt][0][reg];
        aG[mt][1][reg] = sigm(aG[mt][1][reg]+bk1)*l1 + aB[mt][1][reg];
      }
    }
    __syncthreads();
    #pragma unroll
    for (int mt=0; mt<4; mt++){
      #pragma unroll
      for (int reg=0; reg<4; reg++){
        int row = mt*16 + quad*4 + reg;
        SN[row*136 + cg0] = f2bf(aG[mt][0][reg]);
        SN[row*136 + cg1] = f2bf(aG[mt][1][reg]);
      }
    }
    __syncthreads();
  }

  // Q + G (row-major)
  {
    f32x4 aQ_[4][2], aG_[4][2]; ZERO82(aQ_); ZERO82(aG_);
    mm_dual(aQ_, 5, aG_, 6, AQ, PW, wave, lane, lq, quad);
    float bg0 = bg[cg0], bg1 = bg[cg1];
    #pragma unroll
    for (int mt=0; mt<4; mt++){
      #pragma unroll
      for (int reg=0; reg<4; reg++){
        int row = mt*16 + quad*4 + reg;
        Q[(size_t)(rowbase+row)*128 + cg0] = f2bf(aQ_[mt][0][reg]);
        Q[(size_t)(rowbase+row)*128 + cg1] = f2bf(aQ_[mt][1][reg]);
        G[(size_t)(rowbase+row)*128 + cg0] = f2bf(sigm(aG_[mt][0][reg]+bg0));
        G[(size_t)(rowbase+row)*128 + cg1] = f2bf(sigm(aG_[mt][1][reg]+bg1));
      }
    }
  }

  // K (row-major) + VT (transposed)
  {
    f32x4 aK_[4][2], aV_[4][2]; ZERO82(aK_); ZERO82(aV_);
    mm_dual(aK_, 7, aV_, 8, SN, PW, wave, lane, lq, quad);
    #pragma unroll
    for (int mt=0; mt<4; mt++){
      #pragma unroll
      for (int reg=0; reg<4; reg++){
        int row = mt*16 + quad*4 + reg;
        K[(size_t)(rowbase+row)*128 + cg0] = f2bf(aK_[mt][0][reg]);
        K[(size_t)(rowbase+row)*128 + cg1] = f2bf(aK_[mt][1][reg]);
      }
      ushort4 p0, p1;
      p0.x = f2bf(aV_[mt][0][0]); p0.y = f2bf(aV_[mt][0][1]);
      p0.z = f2bf(aV_[mt][0][2]); p0.w = f2bf(aV_[mt][0][3]);
      p1.x = f2bf(aV_[mt][1][0]); p1.y = f2bf(aV_[mt][1][1]);
      p1.z = f2bf(aV_[mt][1][2]); p1.w = f2bf(aV_[mt][1][3]);
      int nloc = nb0 + mt*16 + quad*4;
      *(ushort4*)(VT + ((size_t)(b*128 + cg0))*N_ + nloc) = p0;
      *(ushort4*)(VT + ((size_t)(b*128 + cg1))*N_ + nloc) = p1;
    }
  }
}

// ============================ k2: windowed attention ============================
// 1D grid 1024: flat&7 -> XCD-contiguous window span; wave h owns head h.
__global__ __launch_bounds__(256, 4)
void k2_attn(const float* __restrict__ bo,
             const u16* __restrict__ PW,
             const u16* __restrict__ Q, const u16* __restrict__ K,
             const u16* __restrict__ VT, const u16* __restrict__ G,
             const u16* __restrict__ ADO, const u16* __restrict__ ZB,
             float* __restrict__ gout)
{
  __shared__ char arena[34816];
  u16* ATTall = (u16*)arena;       // 4 x [32][136] bf16 per-wave
  u16* GO     = (u16*)arena;       // [32][136] bf16, aliases ATT after barrier

  const int flat = (int)blockIdx.x;
  const int x = flat & 7, r = flat >> 3;
  const int j = r & 31, b = r >> 5;
  const int i = x*32 + j;

  const int tid = (int)threadIdx.x;
  const int wave = tid >> 6, lane = tid & 63;
  const int lq = lane & 15, quad = lane >> 4;
  const int h = wave;
  const int start = i*32 - 48;
  u16* ATT = ATTall + h*(32*136);

  // -------- logits: L = Q_h @ K_h^T --------
  f32x4 L[2][8];
  #pragma unroll
  for (int mt=0;mt<2;mt++) for (int nt=0;nt<8;nt++) L[mt][nt] = (f32x4)(0.f);
  {
    U16x8 aQ[2];
    #pragma unroll
    for (int mt=0;mt<2;mt++)
      aQ[mt].u4 = *(const uint4*)(Q + ((size_t)b*N_ + i*32 + mt*16 + lq)*128 + h*32 + quad*8);
    #pragma unroll
    for (int nt=0;nt<8;nt++){
      int kr = min(max(start + nt*16 + lq, 0), N_-1);
      U16x8 bk; bk.u4 = *(const uint4*)(K + ((size_t)b*N_ + kr)*128 + h*32 + quad*8);
      L[0][nt] = __builtin_amdgcn_mfma_f32_16x16x32_bf16(aQ[0].v, bk.v, L[0][nt], 0,0,0);
      L[1][nt] = __builtin_amdgcn_mfma_f32_16x16x32_bf16(aQ[1].v, bk.v, L[1][nt], 0,0,0);
    }
  }

  // -------- add precomputed bias (pair + mask) --------
  {
    const u16* zbb = ZB + (size_t)(b*NB_ + i)*16384 + h*4096;
    #pragma unroll
    for (int nt=0;nt<8;nt++){
      #pragma unroll
      for (int mt=0;mt<2;mt++){
        ushort4 z4 = *(const ushort4*)(zbb + (nt*16+lq)*32 + mt*16 + quad*4);
        L[mt][nt][0] += bf2f(z4.x); L[mt][nt][1] += bf2f(z4.y);
        L[mt][nt][2] += bf2f(z4.z); L[mt][nt][3] += bf2f(z4.w);
      }
    }
  }

  // -------- softmax, write attn bf16 into per-wave ATT --------
  #pragma unroll
  for (int mt=0;mt<2;mt++){
    #pragma unroll
    for (int reg=0;reg<4;reg++){
      float mx = -3.0e38f;
      #pragma unroll
      for (int nt=0;nt<8;nt++) mx = fmaxf(mx, L[mt][nt][reg]);
      mx = fmaxf(mx, __shfl_xor(mx,1,16));
      mx = fmaxf(mx, __shfl_xor(mx,2,16));
      mx = fmaxf(mx, __shfl_xor(mx,4,16));
      mx = fmaxf(mx, __shfl_xor(mx,8,16));
      float e[8]; float s = 0.f;
      #pragma unroll
      for (int nt=0;nt<8;nt++){ e[nt] = __expf(L[mt][nt][reg]-mx); s += e[nt]; }
      s += __shfl_xor(s,1,16);
      s += __shfl_xor(s,2,16);
      s += __shfl_xor(s,4,16);
      s += __shfl_xor(s,8,16);
      float inv = 1.f/s;
      int q = mt*16 + quad*4 + reg;
      #pragma unroll
      for (int nt=0;nt<8;nt++) ATT[q*136 + nt*16 + lq] = f2bf(e[nt]*inv);
    }
  }

  // -------- o^T = V_h^T @ attn^T --------
  f32x4 O[2][2];
  O[0][0]=(f32x4)(0.f); O[0][1]=(f32x4)(0.f); O[1][0]=(f32x4)(0.f); O[1][1]=(f32x4)(0.f);
  #pragma unroll
  for (int ks=0;ks<4;ks++){
    U16x8 ba[2];
    #pragma unroll
    for (int nt=0;nt<2;nt++)
      ba[nt].u4 = *(const uint4*)(ATT + (nt*16+lq)*136 + ks*32 + quad*8);
    int kk = start + ks*32 + quad*8;
    kk = min(max(kk,0), N_-8);
    #pragma unroll
    for (int mt=0;mt<2;mt++){
      U16x8 av;
      av.u4 = *(const uint4*)(VT + ((size_t)(b*128 + h*32 + mt*16 + lq))*N_ + kk);
      O[mt][0] = __builtin_amdgcn_mfma_f32_16x16x32_bf16(av.v, ba[0].v, O[mt][0], 0,0,0);
      O[mt][1] = __builtin_amdgcn_mfma_f32_16x16x32_bf16(av.v, ba[1].v, O[mt][1], 0,0,0);
    }
  }
  __syncthreads();   // all waves done reading ATT before GO overwrites arena

  // -------- gate (row-major G), write g*o into GO --------
  #pragma unroll
  for (int mt=0;mt<2;mt++){
    #pragma unroll
    for (int nt=0;nt<2;nt++){
      int q = nt*16 + lq;
      int cb = h*32 + mt*16 + quad*4;
      ushort4 g4 = *(const ushort4*)(G + ((size_t)b*N_ + i*32 + q)*128 + cb);
      ushort4 p;
      p.x = f2bf(bf2f(g4.x)*O[mt][nt][0]); p.y = f2bf(bf2f(g4.y)*O[mt][nt][1]);
      p.z = f2bf(bf2f(g4.z)*O[mt][nt][2]); p.w = f2bf(bf2f(g4.w)*O[mt][nt][3]);
      *(ushort4*)(GO + q*136 + cb) = p;
    }
  }
  __syncthreads();

  // -------- out = sigmoid(ado) * (GO @ Wo + bo) --------
  {
    f32x4 U[2][2];
    U[0][0]=(f32x4)(0.f); U[0][1]=(f32x4)(0.f); U[1][0]=(f32x4)(0.f); U[1][1]=(f32x4)(0.f);
    #pragma unroll
    for (int ks=0;ks<4;ks++){
      U16x8 b0, b1;
      b0.u4 = *(const uint4*)(PW + (size_t)((((9*4+ks)*8) + wave*2+0)*64 + lane)*8);
      b1.u4 = *(const uint4*)(PW + (size_t)((((9*4+ks)*8) + wave*2+1)*64 + lane)*8);
      #pragma unroll
      for (int mt=0;mt<2;mt++){
        U16x8 a; a.u4 = *(const uint4*)(GO + (mt*16+lq)*136 + ks*32 + quad*8);
        U[mt][0] = __builtin_amdgcn_mfma_f32_16x16x32_bf16(a.v, b0.v, U[mt][0], 0,0,0);
        U[mt][1] = __builtin_amdgcn_mfma_f32_16x16x32_bf16(a.v, b1.v, U[mt][1], 0,0,0);
      }
    }
    const int cg0 = wave*32 + lq, cg1 = cg0 + 16;
    float b00 = bo[cg0], b01 = bo[cg1];
    #pragma unroll
    for (int mt=0;mt<2;mt++){
      #pragma unroll
      for (int reg=0;reg<4;reg++){
        int q = mt*16 + quad*4 + reg;
        size_t rowoff = ((size_t)b*N_ + i*32 + q)*128;
        float ad0 = bf2f(ADO[rowoff + cg0]);
        float ad1 = bf2f(ADO[rowoff + cg1]);
        gout[rowoff + cg0] = ad0*(U[mt][0][reg] + b00);
        gout[rowoff + cg1] = ad1*(U[mt][1][reg] + b01);
      }
    }
  }
}

// ============================ launch ============================
extern "C" void kernel_launch(void* const* d_in, const int* in_sizes, int n_in,
                              void* d_out, int out_size, void* d_ws, size_t ws_size,
                              hipStream_t stream) {
  (void)in_sizes; (void)n_in; (void)out_size; (void)ws_size;
  const float* ga    = (const float*)d_in[0];
  const float* gz    = (const float*)d_in[1];
  const float* gs    = (const float*)d_in[2];
  const float* gmask = (const float*)d_in[3];
  const float* lnsqw = (const float*)d_in[4];
  const float* Wgq   = (const float*)d_in[5];
  const float* bgq   = (const float*)d_in[6];
  const float* Wbq   = (const float*)d_in[7];
  const float* lnskw = (const float*)d_in[8];
  const float* Wgk   = (const float*)d_in[9];
  const float* bgk   = (const float*)d_in[10];
  const float* Wbk   = (const float*)d_in[11];
  const float* lnzw  = (const float*)d_in[12];
  const float* lnzb  = (const float*)d_in[13];
  const float* Wz    = (const float*)d_in[14];
  const float* Wq    = (const float*)d_in[15];
  const float* Wk    = (const float*)d_in[16];
  const float* Wv    = (const float*)d_in[17];
  const float* Wg    = (const float*)d_in[18];
  const float* bg    = (const float*)d_in[19];
  const float* Wo    = (const float*)d_in[20];
  const float* bo    = (const float*)d_in[21];
  const float* Wado  = (const float*)d_in[22];
  const float* bado  = (const float*)d_in[23];

  char* ws = (char*)d_ws;
  u16* Qb  = (u16*)(ws + 0);
  u16* Kb  = (u16*)(ws + 8388608);
  u16* VTb = (u16*)(ws + 16777216);
  u16* Gb  = (u16*)(ws + 25165824);
  u16* ADOb= (u16*)(ws + 33554432);
  u16* ZBb = (u16*)(ws + 41943040);
  u16* PW  = (u16*)(ws + 75497472);
  float* AUX = (float*)(ws + 75497472 + 327680);

  k0_prep<<<81 + 8192, 256, 0, stream>>>(Wgq, Wbq, Wgk, Wbk, Wado, Wq, Wg, Wk, Wv, Wo,
                                         lnsqw, lnskw, lnzw, lnzb, Wz, gz, gmask,
                                         PW, AUX, ZBb);
  k1_proj<<<512, 256, 0, stream>>>(ga, gs, bgq, bgk, bg, bado, PW, AUX,
                                   Qb, Kb, VTb, Gb, ADOb);
  k2_attn<<<1024, 256, 0, stream>>>(bo, PW, Qb, Kb, VTb, Gb, ADOb, ZBb, (float*)d_out);
}